// Round 3
// baseline (438.035 us; speedup 1.0000x reference)
//
#include <hip/hip_runtime.h>
#include <hip/hip_bf16.h>
#include <stdint.h>

typedef __attribute__((ext_vector_type(8))) short short8;
typedef __attribute__((ext_vector_type(4))) short short4v;
typedef __attribute__((ext_vector_type(4))) float f32x4;

__device__ inline unsigned short f2bf(float f) {
    union { float f; uint32_t u; } v; v.f = f;
    uint32_t u = v.u;
    uint32_t r = (u + 0x7FFFu + ((u >> 16) & 1u)) >> 16;   // RNE
    return (unsigned short)r;
}

__device__ inline short4v pk4(float4 a) {
    short4v r;
    r[0] = (short)f2bf(a.x); r[1] = (short)f2bf(a.y);
    r[2] = (short)f2bf(a.z); r[3] = (short)f2bf(a.w);
    return r;
}

// ---------------- Router kernel 1: partial GEMM  h_pre = g_in @ W1 -------------
__global__ __launch_bounds__(256) void router1(const float* __restrict__ DKP,
                                               const float* __restrict__ W1,
                                               float* __restrict__ part) {
    __shared__ float gin[16 * 64];
    const int t  = threadIdx.x;
    const int bg = blockIdx.x & 3, jc = blockIdx.x >> 2;
    const int ks = blockIdx.y;
    const int k0 = ks * 64;
    {   // stage g_in chunk [16 b][64 k]
        const int b = t >> 4, q = t & 15;
        *(float4*)(gin + b * 64 + q * 4) =
            *(const float4*)(DKP + (size_t)(bg * 16 + b) * 4096 + k0 + q * 4);
    }
    __syncthreads();
    const int ja = jc * 512 + t, jb = ja + 256;
    float accA[16], accB[16];
    #pragma unroll
    for (int b = 0; b < 16; ++b) { accA[b] = 0.f; accB[b] = 0.f; }
    #pragma unroll 1
    for (int oct = 0; oct < 8; ++oct) {
        const int kk = oct * 8;
        float wa[8], wb[8];
        #pragma unroll
        for (int i = 0; i < 8; ++i) {
            const float* wr = W1 + (size_t)(k0 + kk + i) * 2048;
            wa[i] = wr[ja]; wb[i] = wr[jb];
        }
        #pragma unroll
        for (int b = 0; b < 16; ++b) {
            float4 g0 = *(const float4*)(gin + b * 64 + kk);
            float4 g1 = *(const float4*)(gin + b * 64 + kk + 4);
            accA[b] += g0.x*wa[0] + g0.y*wa[1] + g0.z*wa[2] + g0.w*wa[3]
                     + g1.x*wa[4] + g1.y*wa[5] + g1.z*wa[6] + g1.w*wa[7];
            accB[b] += g0.x*wb[0] + g0.y*wb[1] + g0.z*wb[2] + g0.w*wb[3]
                     + g1.x*wb[4] + g1.y*wb[5] + g1.z*wb[6] + g1.w*wb[7];
        }
    }
    #pragma unroll 1
    for (int b = 0; b < 16; ++b) {
        const size_t row = (size_t)(ks * 64 + bg * 16 + b) * 2048;
        part[row + ja] = accA[b];
        part[row + jb] = accB[b];
    }
}

// ---------------- Router kernel 2: reduce splits + cycle-number col + bias + GELU
__global__ __launch_bounds__(256) void router2(const float* __restrict__ part,
                                               const float* __restrict__ cyc,
                                               const float* __restrict__ W1,
                                               const float* __restrict__ b1,
                                               float* __restrict__ h) {
    const int idx = blockIdx.x * 256 + threadIdx.x;   // idx = b*2048 + j
    const int j = idx & 2047, b = idx >> 11;
    float s = 0.f;
    #pragma unroll 8
    for (int t = 0; t < 64; ++t)
        s += part[((size_t)t * 64 + b) * 2048 + j];
    s += cyc[b] * W1[(size_t)4096 * 2048 + j] + b1[j];
    const float u  = s + 0.044715f * s * s * s;
    const float th = tanhf(0.7978845608028654f * u);
    h[idx] = 0.5f * s * (1.0f + th);
}

// ---------------- Router kernel 3: logits, top-2, softmax, renorm gates -------
__global__ __launch_bounds__(256) void router3(const float* __restrict__ h,
                                               const float* __restrict__ W2,
                                               const float* __restrict__ b2,
                                               float4* __restrict__ gates) {
    __shared__ float red[256 * 8];
    __shared__ float lg[8];
    const int b = blockIdx.x, t = threadIdx.x;
    float acc[8];
    #pragma unroll
    for (int e = 0; e < 8; ++e) acc[e] = 0.f;
    for (int k = t; k < 2048; k += 256) {
        const float hv = h[(size_t)b * 2048 + k];
        const float* w = W2 + (size_t)k * 8;
        #pragma unroll
        for (int e = 0; e < 8; ++e) acc[e] += hv * w[e];
    }
    #pragma unroll
    for (int e = 0; e < 8; ++e) red[t * 8 + e] = acc[e];
    __syncthreads();
    if (t < 8) {
        float s = 0.f;
        for (int r = 0; r < 256; ++r) s += red[r * 8 + t];
        lg[t] = s + b2[t];
    }
    __syncthreads();
    if (t == 0) {
        float l[8];
        #pragma unroll
        for (int e = 0; e < 8; ++e) l[e] = lg[e];
        int e0 = 0;
        #pragma unroll
        for (int e = 1; e < 8; ++e) if (l[e] > l[e0]) e0 = e;
        int e1 = (e0 == 0) ? 1 : 0;
        #pragma unroll
        for (int e = 0; e < 8; ++e) if (e != e0 && l[e] > l[e1]) e1 = e;
        const float m = l[e0];
        float p[8], Z = 0.f;
        #pragma unroll
        for (int e = 0; e < 8; ++e) { p[e] = expf(l[e] - m); Z += p[e]; }
        const float pe0 = p[e0] / Z, pe1 = p[e1] / Z;
        const float s2 = pe0 + pe1 + 1e-9f;
        gates[b] = make_float4(__int_as_float(e0), __int_as_float(e1), pe0 / s2, pe1 / s2);
    }
}

// ---------------- Combine weights: Wcomb^T[b][d][i], bf16, K-pad to 928 -------
__global__ __launch_bounds__(256) void combine_w(const float* __restrict__ genW,
                                                 const float* __restrict__ expW,
                                                 const float4* __restrict__ gates,
                                                 unsigned short* __restrict__ wc) {
    __shared__ unsigned short T[64 * 72];
    const int b  = blockIdx.z;
    const int i0 = blockIdx.y * 64;
    const int d0 = blockIdx.x * 64;
    const float4 gt = gates[b];
    const int e0 = __float_as_int(gt.x), e1 = __float_as_int(gt.y);
    const float g0 = gt.z, g1 = gt.w;
    const float* W0 = expW + (size_t)e0 * 900 * 512;
    const float* W1e = expW + (size_t)e1 * 900 * 512;
    const int t = threadIdx.x;
    {
        const int il = t >> 2, c = t & 3;
        const int i = i0 + il;
        const bool valid = (i < 900);
        const size_t rowoff = (size_t)i * 512 + d0 + c * 16;
        #pragma unroll
        for (int s = 0; s < 4; ++s) {
            float4 g  = valid ? *(const float4*)(genW + rowoff + 4 * s) : make_float4(0,0,0,0);
            float4 w0 = valid ? *(const float4*)(W0   + rowoff + 4 * s) : make_float4(0,0,0,0);
            float4 w1 = valid ? *(const float4*)(W1e  + rowoff + 4 * s) : make_float4(0,0,0,0);
            const int dl = c * 16 + 4 * s;
            T[(dl + 0) * 72 + il] = f2bf(g.x + g0 * w0.x + g1 * w1.x);
            T[(dl + 1) * 72 + il] = f2bf(g.y + g0 * w0.y + g1 * w1.y);
            T[(dl + 2) * 72 + il] = f2bf(g.z + g0 * w0.z + g1 * w1.z);
            T[(dl + 3) * 72 + il] = f2bf(g.w + g0 * w0.w + g1 * w1.w);
        }
    }
    __syncthreads();
    {
        const int dl = t >> 2, seg = t & 3;
        const int ic = seg * 16;
        if (i0 + ic < 928) {
            short8 v0 = *(const short8*)&T[dl * 72 + ic];
            short8 v1 = *(const short8*)&T[dl * 72 + ic + 8];
            unsigned short* dst = wc + (size_t)b * 512 * 928 + (size_t)(d0 + dl) * 928 + i0 + ic;
            *(short8*)dst = v0;
            *((short8*)dst + 1) = v1;
        }
    }
}

// ---------------- Main fused batched GEMM: out[b] = x[b] @ Wcomb_b + bias ------
// 128x128 tile, 256 thr / 4 waves (2x2 of 64x64), BK=32, double-buffered LDS,
// ONE barrier per K-iter. Next tile's B goes via global_load_lds and A via f32
// VGPR prefetch at iter start; A cvt+ds_write happens AFTER the MFMA phase so
// the barrier's vmcnt(0) drain waits on loads that already overlapped compute.
// Both As and Bs are 16B-slot XOR-swizzled (slot = seg ^ ((row>>1)&3)): frag
// ds_read_b128 lands 2-way on banks (free) instead of 4-8 way.
__global__ __launch_bounds__(256, 4) void moe_gemm(const float* __restrict__ x,
                                                   const unsigned short* __restrict__ wc,
                                                   const float4* __restrict__ gates,
                                                   const float* __restrict__ eb,
                                                   const float* __restrict__ genb,
                                                   float* __restrict__ out) {
    __shared__ unsigned short As[2][128 * 32];
    __shared__ unsigned short Bs[2][128 * 32];
    const int b    = blockIdx.x;
    const int tile = blockIdx.y;
    const int m0 = (tile >> 2) * 128, n0 = (tile & 3) * 128;
    const int t = threadIdx.x, lane = t & 63, wid = t >> 6;
    const float4 gt = gates[b];
    const int e0 = __float_as_int(gt.x), e1 = __float_as_int(gt.y);
    const float g0 = gt.z, g1 = gt.w;
    const float* xb = x + (size_t)b * 512 * 900;
    const unsigned short* wcb = wc + (size_t)b * 512 * 928;

    f32x4 acc[4][4];
    #pragma unroll
    for (int mi = 0; mi < 4; ++mi)
        #pragma unroll
        for (int ni = 0; ni < 4; ++ni)
            acc[mi][ni] = (f32x4){0.f, 0.f, 0.f, 0.f};

    // A staging: thread -> row ar = t>>1 (0..127), half ah = t&1 (16 floats)
    const int ar = t >> 1, ah = t & 1;
    const float* xrow = xb + (size_t)(m0 + ar) * 900 + ah * 16;
    const int fa = (ar >> 1) & 3;
    // B staging: lane -> row bu = lane>>2 in 16-row chunk, slot bsl = lane&3
    const int bu = lane >> 2, bsl = lane & 3;
    const int bseg = bsl ^ ((bu >> 1) & 3);

    const int wm = (wid >> 1) * 64, wn = (wid & 1) * 64;
    const int lm = lane & 15, lq = lane >> 4;
    const int fslot = (lq ^ ((lm >> 1) & 3)) * 8;

    float4 apf[4];

    #define LOAD_A(K0)                                                          \
        {   const int _k0 = (K0);                                               \
            _Pragma("unroll")                                                   \
            for (int q = 0; q < 4; ++q) {                                       \
                const int k = _k0 + ah * 16 + q * 4;                            \
                apf[q] = (k + 4 <= 900) ? *(const float4*)(xrow + _k0 + q * 4)  \
                                        : make_float4(0.f, 0.f, 0.f, 0.f);      \
            }                                                                   \
        }
    #define WRITE_A(BUF)                                                        \
        {   _Pragma("unroll")                                                   \
            for (int q = 0; q < 4; ++q) {                                       \
                const int koff = ah * 16 + q * 4;                               \
                const int sl = (koff >> 3) ^ fa;                                \
                *(short4v*)&As[BUF][ar * 32 + sl * 8 + (koff & 7)] = pk4(apf[q]); \
            }                                                                   \
        }
    #define STAGE_B(K0, BUF)                                                    \
        {   const int _k0 = (K0);                                               \
            _Pragma("unroll")                                                   \
            for (int r2 = 0; r2 < 2; ++r2) {                                    \
                const int chunk = wid * 2 + r2;                                 \
                const unsigned short* gsrc =                                    \
                    wcb + (size_t)(n0 + chunk * 16 + bu) * 928 + _k0 + bseg * 8;\
                __builtin_amdgcn_global_load_lds(                               \
                    (const __attribute__((address_space(1))) unsigned int*)gsrc,\
                    (__attribute__((address_space(3))) unsigned int*)            \
                        (&Bs[BUF][chunk * 512]), 16, 0, 0);                     \
            }                                                                   \
        }

    LOAD_A(0); STAGE_B(0, 0); WRITE_A(0);
    __syncthreads();

    int cur = 0;
    for (int kt = 0; kt < 29; ++kt) {
        const int nxt = cur ^ 1;
        if (kt < 28) { LOAD_A((kt + 1) * 32); STAGE_B((kt + 1) * 32, nxt); }
        short8 af[4], bfr[4];
        #pragma unroll
        for (int mi = 0; mi < 4; ++mi)
            af[mi] = *(const short8*)&As[cur][(wm + mi * 16 + lm) * 32 + fslot];
        #pragma unroll
        for (int ni = 0; ni < 4; ++ni)
            bfr[ni] = *(const short8*)&Bs[cur][(wn + ni * 16 + lm) * 32 + fslot];
        #pragma unroll
        for (int mi = 0; mi < 4; ++mi)
            #pragma unroll
            for (int ni = 0; ni < 4; ++ni)
                acc[mi][ni] = __builtin_amdgcn_mfma_f32_16x16x32_bf16(
                    af[mi], bfr[ni], acc[mi][ni], 0, 0, 0);
        if (kt < 28) WRITE_A(nxt);
        __syncthreads();
        cur = nxt;
    }

    // ---- Epilogue
    #pragma unroll
    for (int ni = 0; ni < 4; ++ni) {
        const int col = n0 + wn + ni * 16 + lm;
        const float bias = genb[col] + g0 * eb[e0 * 512 + col] + g1 * eb[e1 * 512 + col];
        #pragma unroll
        for (int mi = 0; mi < 4; ++mi) {
            const int row = m0 + wm + mi * 16 + lq * 4;
            #pragma unroll
            for (int r = 0; r < 4; ++r)
                out[((size_t)b * 512 + row + r) * 512 + col] = acc[mi][ni][r] + bias;
        }
    }
    #undef LOAD_A
    #undef WRITE_A
    #undef STAGE_B
}

extern "C" void kernel_launch(void* const* d_in, const int* in_sizes, int n_in,
                              void* d_out, int out_size, void* d_ws, size_t ws_size,
                              hipStream_t stream) {
    const float* x    = (const float*)d_in[0];   // [64][512][900]
    const float* cyc  = (const float*)d_in[1];   // [64][1]
    const float* dkp  = (const float*)d_in[2];   // [64][4096]
    const float* gW1  = (const float*)d_in[3];   // [4097][2048]
    const float* gb1  = (const float*)d_in[4];   // [2048]
    const float* gW2  = (const float*)d_in[5];   // [2048][8]
    const float* gb2  = (const float*)d_in[6];   // [8]
    const float* eW   = (const float*)d_in[7];   // [8][900][512]
    const float* eb   = (const float*)d_in[8];   // [8][512]
    const float* genW = (const float*)d_in[9];   // [900][512]
    const float* genb = (const float*)d_in[10];  // [512]
    float* out = (float*)d_out;                  // [64][512][512] f32

    char* ws = (char*)d_ws;
    // ws: [0, 60817408) Wcomb bf16 [64][512][928]; partials (33.5MB) alias it
    // (dead before combine_w). Then h (512KB), gates (1KB).
    unsigned short* wcomb = (unsigned short*)ws;
    float* part  = (float*)ws;                          // [64][64][2048] f32
    float* h     = (float*)(ws + 60817408);             // [64][2048] f32
    float4* gts  = (float4*)(ws + 60817408 + 524288);   // [64] {e0,e1,g0,g1}

    router1<<<dim3(16, 64), 256, 0, stream>>>(dkp, gW1, part);
    router2<<<512, 256, 0, stream>>>(part, cyc, gW1, gb1, h);
    router3<<<64, 256, 0, stream>>>(h, gW2, gb2, gts);
    combine_w<<<dim3(8, 15, 64), 256, 0, stream>>>(genW, eW, gts, wcomb);
    moe_gemm<<<dim3(64, 16), 256, 0, stream>>>(x, wcomb, gts, eb, genb, out);
}